// Round 2
// baseline (67.617 us; speedup 1.0000x reference)
//
#include <hip/hip_runtime.h>

// Problem constants (derived from the reference, fixed shapes)
#define NFFT  4096
#define HOP   1024
#define T_IN  441000          // input samples per (b,c)
#define L1    444416          // length after first reflect pad (1536, 1880)
#define LP    448512          // length after second reflect pad (2048, 2048)
#define PAD1  1536
#define P2    2048
#define NF    435             // ISTFT frame count
#define F_LO  2               // first non-zero frame
#define F_HI  432             // last non-zero frame (inclusive)
#define BC    16              // B*C
#define POS0  3584            // output g -> OLA position g + 3584

// Compose the two reflect-pads: xpad[m] = x[map_idx(m)], m in [0, LP)
__device__ __forceinline__ int map_idx(int m) {
    int a = m - P2;
    if (a < 0) a = -a;                       // left reflect of 2nd pad
    else if (a >= L1) a = 2 * L1 - 2 - a;    // right reflect of 2nd pad
    int b = a - PAD1;
    if (b < 0) b = -b;                       // left reflect of 1st pad
    else if (b >= T_IN) b = 2 * T_IN - 2 - b;
    return b;
}

// Hann window table, indices 0..NFFT (win[NFFT]=0, periodic guard)
__global__ void build_win_kernel(float* __restrict__ win) {
    int n = blockIdx.x * blockDim.x + threadIdx.x;
    if (n <= NFFT) {
        float v = 0.5f - 0.5f * cosf(6.28318530717958647692f * (float)n / (float)NFFT);
        if (n == 0 || n == NFFT) v = 0.0f;
        win[n] = v;
    }
}

// Per-frame even/odd windowed sums:
//   E_f = sum_{n even} xpad[1024f+n]*win[n],  O_f = sum_{n odd} ...
// Layout: eo[(bc*NF + f)*2 + 0] = O (used when t even), +1 = E (t odd)
__global__ void frame_sums_kernel(const float* __restrict__ x,
                                  const float* __restrict__ win,
                                  float* __restrict__ eo) {
    int f  = blockIdx.x + F_LO;   // 2..432
    int bc = blockIdx.y;
    const float* xb = x + bc * T_IN;
    int base = f * HOP;
    float s = 0.0f;
    for (int n = threadIdx.x; n < NFFT; n += 256)
        s += xb[map_idx(base + n)] * win[n];    // n parity == threadIdx.x parity
    // parity-preserving wave reduce: offsets 32..2 keep even/odd lanes separate
    for (int off = 32; off >= 2; off >>= 1)
        s += __shfl_down(s, off, 64);
    __shared__ float red[2][4];
    int wave = threadIdx.x >> 6;
    int lane = threadIdx.x & 63;
    if (lane < 2) red[lane][wave] = s;
    __syncthreads();
    if (threadIdx.x < 2) {
        float t = red[threadIdx.x][0] + red[threadIdx.x][1] +
                  red[threadIdx.x][2] + red[threadIdx.x][3];
        // threadIdx.x==0 -> even-n sum (E) -> slot 1 ; ==1 -> odd-n (O) -> slot 0
        eo[(bc * NF + f) * 2 + (threadIdx.x ^ 1)] = t;
    }
}

// Main: out[bc, g] = (2/3) * sum_{j in frames covering pos} win[t] *
//        ( 2048 * win[4096 - t] * xpad[1024*j + 4096 - t] + (t odd ? E_j : O_j) )
// with pos = g + 3584, t = pos - 1024*j, j clamped to [2, 432].
__global__ void main_kernel(const float* __restrict__ x,
                            const float* __restrict__ win,
                            const float* __restrict__ eo,
                            float* __restrict__ out) {
    int g  = blockIdx.x * blockDim.x + threadIdx.x;
    int bc = blockIdx.y;
    if (g >= T_IN) return;
    int pos = g + POS0;
    int jhi = pos >> 10;
    int jlo = jhi - 3;
    if (jlo < F_LO) jlo = F_LO;
    int jh = jhi > F_HI ? F_HI : jhi;
    const float* xb  = x + bc * T_IN;
    const float* eob = eo + bc * NF * 2;
    float acc = 0.0f;
    for (int j = jlo; j <= jh; ++j) {
        int t = pos - (j << 10);          // 0..4095
        int r = NFFT - t;                 // 1..4096 (t=0 -> wt=0, term vanishes)
        float wt = win[t];
        float wr = win[r];
        float xv = xb[map_idx(j * HOP + r)];
        float p  = eob[(j << 1) | (t & 1)];
        acc += wt * (2048.0f * wr * xv + p);
    }
    out[(size_t)bc * T_IN + g] = acc * (2.0f / 3.0f);
}

extern "C" void kernel_launch(void* const* d_in, const int* in_sizes, int n_in,
                              void* d_out, int out_size, void* d_ws, size_t ws_size,
                              hipStream_t stream) {
    const float* x = (const float*)d_in[0];   // mix (8,2,441000) fp32
    // d_in[1], d_in[2] (basis_real/imag) are not needed: transforms composed analytically.
    float* out = (float*)d_out;

    float* win = (float*)d_ws;                 // (NFFT+1) floats
    float* eo  = win + 8192;                   // 32KB offset; BC*NF*2 floats (~56KB)

    build_win_kernel<<<(NFFT + 256) / 256, 256, 0, stream>>>(win);
    frame_sums_kernel<<<dim3(F_HI - F_LO + 1, BC), 256, 0, stream>>>(x, win, eo);
    main_kernel<<<dim3((T_IN + 255) / 256, BC), 256, 0, stream>>>(x, win, eo, out);
}

// Round 3
// 36.975 us; speedup vs baseline: 1.8287x; 1.8287x over previous
//
#include <hip/hip_runtime.h>

// Fixed problem constants
#define NFFT  4096
#define HOP   1024
#define T_IN  441000          // samples per (b,c)
#define L1    444416          // after 1st reflect pad
#define PAD1  1536
#define P2    2048
#define NSEG  436             // hop segments 0..435 (we use 2..435)
#define BC    16              // B*C
#define POS0  3584            // output g -> OLA position g + 3584
#define F_LO  2
#define F_HI  432

// Composed reflect-pads: xpad[m] = x[map_idx(m)]
__device__ __forceinline__ int map_idx(int m) {
    int a = m - P2;
    if (a < 0) a = -a;
    else if (a >= L1) a = 2 * L1 - 2 - a;
    int b = a - PAD1;
    if (b < 0) b = -b;
    else if (b >= T_IN) b = 2 * T_IN - 2 - b;
    return b;
}

// Hann table win[0..4096], symmetric: win[4096-t] == win[t]
__global__ void build_win_kernel(float* __restrict__ win) {
    int n = blockIdx.x * blockDim.x + threadIdx.x;
    if (n <= NFFT) {
        float v = 0.5f - 0.5f * cosf(6.28318530717958647692f * (float)n / (float)NFFT);
        if (n == 0 || n == NFFT) v = 0.0f;
        win[n] = v;
    }
}

// Segment partials: P[bc][s][q*2+par] = sum_{n_local in seg, n_local&1==par}
//   xpad[1024*s + n_local] * win[1024*q + n_local]
// One wave per segment; x read ONCE (float4 fast path for interior segments).
__global__ void seg_partials_kernel(const float* __restrict__ x,
                                    const float* __restrict__ win,
                                    float* __restrict__ P) {
    const int wave = threadIdx.x >> 6;
    const int lane = threadIdx.x & 63;
    const int s = 2 + blockIdx.x * 4 + wave;
    if (s > 435) return;
    const int bc = blockIdx.y;
    const float* xb = x + (size_t)bc * T_IN;
    const int base = s * HOP - POS0;            // identity x index for n_local=0
    const bool fastseg = (s >= 4 && s <= 433);  // no reflection inside segment
    float sE0=0,sE1=0,sE2=0,sE3=0,sO0=0,sO1=0,sO2=0,sO3=0;
    #pragma unroll
    for (int i = 0; i < 4; ++i) {
        const int nl = i * 256 + lane * 4;      // coalesced float4 per lane
        float4 xv;
        if (fastseg) {
            xv = *reinterpret_cast<const float4*>(xb + base + nl);
        } else {
            const int m = s * HOP + nl;
            xv.x = xb[map_idx(m)];
            xv.y = xb[map_idx(m + 1)];
            xv.z = xb[map_idx(m + 2)];
            xv.w = xb[map_idx(m + 3)];
        }
        const float4 w0 = *reinterpret_cast<const float4*>(win + nl);
        const float4 w1 = *reinterpret_cast<const float4*>(win + 1024 + nl);
        const float4 w2 = *reinterpret_cast<const float4*>(win + 2048 + nl);
        const float4 w3 = *reinterpret_cast<const float4*>(win + 3072 + nl);
        sE0 += xv.x*w0.x + xv.z*w0.z;  sO0 += xv.y*w0.y + xv.w*w0.w;
        sE1 += xv.x*w1.x + xv.z*w1.z;  sO1 += xv.y*w1.y + xv.w*w1.w;
        sE2 += xv.x*w2.x + xv.z*w2.z;  sO2 += xv.y*w2.y + xv.w*w2.w;
        sE3 += xv.x*w3.x + xv.z*w3.z;  sO3 += xv.y*w3.y + xv.w*w3.w;
    }
    #pragma unroll
    for (int off = 32; off; off >>= 1) {
        sE0 += __shfl_down(sE0, off, 64); sO0 += __shfl_down(sO0, off, 64);
        sE1 += __shfl_down(sE1, off, 64); sO1 += __shfl_down(sO1, off, 64);
        sE2 += __shfl_down(sE2, off, 64); sO2 += __shfl_down(sO2, off, 64);
        sE3 += __shfl_down(sE3, off, 64); sO3 += __shfl_down(sO3, off, 64);
    }
    if (lane == 0) {
        float* Pp = P + ((size_t)bc * NSEG + s) * 8;
        Pp[0]=sE0; Pp[1]=sO0; Pp[2]=sE1; Pp[3]=sO1;
        Pp[4]=sE2; Pp[5]=sO2; Pp[6]=sE3; Pp[7]=sO3;
    }
}

// Main: out[g] = (2/3) * sum_{j covering pos} win[t] * (2048*win[t]*x[2048j-3072-g] + p_j)
// (win[4096-t]==win[t]; p_j = E_j if t odd else O_j, recombined from P)
// 512 outputs per block -> covering frames block-uniform -> branch-free fast path.
__global__ void __launch_bounds__(256) main_kernel(const float* __restrict__ x,
                            const float* __restrict__ win,
                            const float* __restrict__ P,
                            float* __restrict__ out) {
    const int g0 = blockIdx.x * 512;
    const int bc = blockIdx.y;
    const int tid = threadIdx.x;
    const float* xb = x + (size_t)bc * T_IN;
    const float* Pb = P + (size_t)bc * NSEG * 8;
    float* ob = out + (size_t)bc * T_IN;
    const int pos0 = g0 + POS0;
    const int jhi = pos0 >> 10;                 // uniform over 512-aligned block
    const int jlo = jhi - 3;
    const bool fast = (jlo >= F_LO) && (jhi <= F_HI)
                   && (2048 * jlo - 3072 - (g0 + 511) >= 0)
                   && (2048 * jhi - 3072 - g0 < T_IN);
    if (fast) {
        const int slot = (tid & 1) ^ 1;         // pos parity == tid parity here
        const float c23 = 2.0f / 3.0f;
        const float K = 4096.0f / 3.0f;         // 2048 * 2/3
        float pp[4];
        #pragma unroll
        for (int jj = 0; jj < 4; ++jj) {
            const float* q = Pb + (jlo + jj) * 8 + slot;
            pp[jj] = c23 * (q[0] + q[10] + q[20] + q[30]);  // E/O = sum of 4 quarter partials
        }
        #pragma unroll
        for (int k = 0; k < 2; ++k) {
            const int g = g0 + tid + 256 * k;
            const int pos = g + POS0;
            float acc = 0.0f;
            #pragma unroll
            for (int jj = 0; jj < 4; ++jj) {
                const int j = jlo + jj;
                const int t = pos - (j << 10);            // 0..4095
                const float w = win[t];
                const float xv = xb[2048 * j - 3072 - g]; // reversed-coalesced
                acc = fmaf(w, fmaf(K * w, xv, pp[jj]), acc);
            }
            ob[g] = acc;
        }
    } else {
        #pragma unroll
        for (int k = 0; k < 2; ++k) {
            const int g = g0 + tid + 256 * k;
            if (g >= T_IN) continue;
            const int pos = g + POS0;
            int jh = pos >> 10;
            int jl = jh - 3;
            if (jl < F_LO) jl = F_LO;
            if (jh > F_HI) jh = F_HI;
            const int slot = (pos & 1) ^ 1;
            float acc = 0.0f;
            for (int j = jl; j <= jh; ++j) {
                const int t = pos - (j << 10);
                const int r = NFFT - t;
                const float w = win[t];                   // == win[r] by symmetry
                const float xv = xb[map_idx(j * HOP + r)];
                const float* q = Pb + j * 8 + slot;
                const float p = q[0] + q[10] + q[20] + q[30];
                acc += w * (2048.0f * w * xv + p);
            }
            ob[g] = acc * (2.0f / 3.0f);
        }
    }
}

extern "C" void kernel_launch(void* const* d_in, const int* in_sizes, int n_in,
                              void* d_out, int out_size, void* d_ws, size_t ws_size,
                              hipStream_t stream) {
    const float* x = (const float*)d_in[0];   // mix (8,2,441000) fp32
    float* out = (float*)d_out;

    float* win = (float*)d_ws;                // 4097 floats (padded to 8192)
    float* Pw  = win + 8192;                  // BC*NSEG*8 floats (~218 KB)

    build_win_kernel<<<17, 256, 0, stream>>>(win);
    seg_partials_kernel<<<dim3(109, BC), 256, 0, stream>>>(x, win, Pw);
    main_kernel<<<dim3(862, BC), 256, 0, stream>>>(x, win, Pw, out);
}